// Round 11
// baseline (229.502 us; speedup 1.0000x reference)
//
#include <hip/hip_runtime.h>
#include <hip/hip_bf16.h>
#include <math.h>

#define BD 8      // B
#define LD 256    // L
#define DM 256    // D_MODEL
#define DS 16     // D_STATE
#define DI 512    // D_INNER
#define RK 16     // DT_RANK

#define NROWS (2*BD*LD)   // 4096 rows (both branches concatenated)
#define HALF_ROWS (BD*LD) // 2048

typedef __attribute__((ext_vector_type(8))) short bhalf8;   // 8 bf16 = 4 VGPR
typedef __attribute__((ext_vector_type(4))) float f32x4;

__device__ __forceinline__ float siluf(float x){ return x / (1.f + __expf(-x)); }
__device__ __forceinline__ float softplusf(float x){
  return fmaxf(x, 0.f) + log1pf(__expf(-fabsf(x)));
}
__device__ __forceinline__ unsigned short f2bf(float f){
  __hip_bfloat16 h = __float2bfloat16(f);   // RNE
  return *reinterpret_cast<unsigned short*>(&h);
}

// Fragment-ordered weight layout: flat = ((ct*(K/32)+ks)*64 + quad*16 + m16)*8 + j
// so a wave B-load is W + f*512 + lane*8  (fully coalesced 1KB).
// Transposed activation layout: T[(bb*C + col)*LD + l], bb = global batch 0..15.

// ================= prep: weights -> fragment-order bf16, LN of x, zero pooled =================
__global__ __launch_bounds__(256) void k_prep(
    const float* __restrict__ Wi_spa, const float* __restrict__ Wi_spe,
    const float* __restrict__ Wo_spa, const float* __restrict__ Wo_spe,
    const float* __restrict__ scW,
    const float* __restrict__ Wx_spa, const float* __restrict__ Wx_spe,
    const float* __restrict__ x_spa, const float* __restrict__ x_spe,
    const float* __restrict__ g_spa, const float* __restrict__ b_spa,
    const float* __restrict__ g_spe, const float* __restrict__ b_spe,
    unsigned short* __restrict__ Wt_i_spa, unsigned short* __restrict__ Wt_i_spe,
    unsigned short* __restrict__ Wt_o_spa, unsigned short* __restrict__ Wt_o_spe,
    unsigned short* __restrict__ scWt,
    unsigned short* __restrict__ Wxt_spa, unsigned short* __restrict__ Wxt_spe,
    unsigned short* __restrict__ xnbf, unsigned short* __restrict__ xbf,
    float* __restrict__ pooled)
{
  __shared__ __align__(16) unsigned char smem[59904];
  int b = blockIdx.x;
  int tid = threadIdx.x;
  if (b == 60){
    for (int i=tid; i<BD*DM; i+=256) pooled[i] = 0.f;
    return;
  }
  if (b >= 61){
    float (*xst)[260] = (float (*)[260])smem;
    float (*red)[16]  = (float (*)[16])(smem + 16640);
    float *mu = (float*)(smem + 17664);
    float *rs = (float*)(smem + 17728);
    int r0g = (b - 61) * 16;
    int branch = r0g >= HALF_ROWS;
    const float* xb = branch ? x_spe : x_spa;
    const float* g  = branch ? g_spe : g_spa;
    const float* be = branch ? b_spe : b_spa;
    int rr0 = branch ? r0g - HALF_ROWS : r0g;
    for (int p=0;p<4;p++){
      int i4 = tid + 256*p;
      int r = i4 >> 6, c4 = (i4 & 63)*4;
      *(float4*)&xst[r][c4] = *(const float4*)(xb + (rr0+r)*DM + c4);
    }
    __syncthreads();
    {
      int row = tid >> 4, seg = tid & 15;
      float s = 0.f, s2 = 0.f;
      #pragma unroll
      for (int i=0;i<4;i++){
        float4 v = *(float4*)&xst[row][seg*16 + i*4];
        s  += v.x+v.y+v.z+v.w;
        s2 += v.x*v.x + v.y*v.y + v.z*v.z + v.w*v.w;
      }
      red[row][seg] = s;
      __syncthreads();
      if (seg == 0){
        float t=0.f;
        #pragma unroll
        for (int i=0;i<16;i++) t += red[row][i];
        mu[row] = t * (1.f/DM);
      }
      __syncthreads();
      red[row][seg] = s2;
      __syncthreads();
      if (seg == 0){
        float t=0.f;
        #pragma unroll
        for (int i=0;i<16;i++) t += red[row][i];
        float m = mu[row];
        rs[row] = rsqrtf(t*(1.f/DM) - m*m + 1e-6f);
      }
    }
    __syncthreads();
    for (int p=0;p<4;p++){
      int i4 = tid + 256*p;
      int r = i4 >> 6, c4 = (i4 & 63)*4;
      float4 v  = *(float4*)&xst[r][c4];
      float4 gv = *(const float4*)(g + c4);
      float4 bv = *(const float4*)(be + c4);
      float m = mu[r], rv = rs[r];
      unsigned int rlo = (unsigned int)f2bf(v.x) | ((unsigned int)f2bf(v.y) << 16);
      unsigned int rhi = (unsigned int)f2bf(v.z) | ((unsigned int)f2bf(v.w) << 16);
      *(uint2*)&xbf[(r0g+r)*DM + c4] = make_uint2(rlo, rhi);
      unsigned int nlo = (unsigned int)f2bf((v.x-m)*rv*gv.x + bv.x)
                       | ((unsigned int)f2bf((v.y-m)*rv*gv.y + bv.y) << 16);
      unsigned int nhi = (unsigned int)f2bf((v.z-m)*rv*gv.z + bv.z)
                       | ((unsigned int)f2bf((v.w-m)*rv*gv.w + bv.w) << 16);
      *(uint2*)&xnbf[(r0g+r)*DM + c4] = make_uint2(nlo, nhi);
    }
    return;
  }
  if (b >= 52){
    int bb = b - 52;
    int branch = bb >> 2, chunk = bb & 3;
    int k0 = chunk*128;
    const float* Wx = branch ? Wx_spe : Wx_spa;
    unsigned short* Wxt = branch ? Wxt_spe : Wxt_spa;
    float (*tile2)[49] = (float (*)[49])(smem + 34816);
    for (int i=tid; i<128*48; i+=256){
      int kk = i/48, c = i - kk*48;
      tile2[kk][c] = Wx[(k0+kk)*48 + c];
    }
    __syncthreads();
    for (int i=tid; i<64*128; i+=256){
      int cc = i >> 7, kk = i & 127;
      float v = (cc < 48) ? tile2[kk][cc] : 0.f;
      int kg = k0 + kk;
      int ct = cc >> 4, m16 = cc & 15;
      int ks = kg >> 5, quad = (kg >> 3) & 3, j = kg & 7;
      Wxt[((ct*16 + ks)*64 + quad*16 + m16)*8 + j] = f2bf(v);
    }
    return;
  }
  unsigned short (*tile)[68] = (unsigned short (*)[68])smem;
  const float* W; unsigned short* Wt; int N, K, c0, k0;
  if (b < 32){
    int bb = b & 15;
    W  = (b < 16) ? Wi_spa  : Wi_spe;
    Wt = (b < 16) ? Wt_i_spa: Wt_i_spe;
    N = 1024; K = 256; c0 = (bb >> 2)*256; k0 = (bb & 3)*64;
  } else if (b < 48){
    int bb = b - 32; int h = bb >> 3; bb &= 7;
    W  = h ? Wo_spe  : Wo_spa;
    Wt = h ? Wt_o_spe: Wt_o_spa;
    N = 256; K = 512; c0 = 0; k0 = bb*64;
  } else {
    int bb = b - 48;
    W = scW; Wt = scWt;
    N = 256; K = 256; c0 = 0; k0 = bb*64;
  }
  int c = c0 + tid;
  #pragma unroll 8
  for (int kk=0; kk<64; kk++)
    tile[tid][kk] = f2bf(W[(k0+kk)*N + c]);
  __syncthreads();
  int ksegs = K >> 5;
  for (int p=0; p<16; p++){
    int i = tid + 256*p;
    int cl = i >> 4, kq = (i & 15)*4;
    int cg = c0 + cl;
    int ct = cg >> 4, m16 = cg & 15;
    int kg = k0 + kq;
    int ks = kg >> 5, quad = (kg >> 3) & 3, j = kg & 7;
    uint2 v = *(const uint2*)&tile[cl][kq];
    *(uint2*)&Wt[((ct*ksegs + ks)*64 + quad*16 + m16)*8 + j] = v;
  }
}

// ================= merged W_in GEMM (bi<1024, transposed out) + shortcut GEMM+LN =================
__global__ __launch_bounds__(256) void k_gemm1(
    const unsigned short* __restrict__ xnbf, const unsigned short* __restrict__ xbf,
    const unsigned short* __restrict__ Wt_spa, const unsigned short* __restrict__ Wt_spe,
    const unsigned short* __restrict__ scWt, const float* __restrict__ sc_b,
    const float* __restrict__ ln_g, const float* __restrict__ ln_b,
    float* __restrict__ xcrT, float* __restrict__ szT, float* __restrict__ ident)
{
  __shared__ unsigned short At[16][264];   // 8.4 KB
  __shared__ float Dt[16][260];            // 16.6 KB (shortcut only)
  __shared__ float red[16][16];
  __shared__ float mu[16], rs[16];
  int tid = threadIdx.x;
  int bi = blockIdx.x;
  int w = tid >> 6, lane = tid & 63;
  int m16 = lane & 15, quad = lane >> 4;
  if (bi < 1024){
    int rg = bi >> 2, cg = bi & 3;
    int r0 = rg * 16;
    int branch = (r0 >= HALF_ROWS);
    const unsigned short* Wt = branch ? Wt_spe : Wt_spa;
    for (int p=0;p<2;p++){
      int i = tid + 256*p;
      int r = i >> 5, oct = (i & 31)*8;
      *(uint4*)&At[r][oct] = *(const uint4*)&xnbf[(r0+r)*DM + oct];
    }
    __syncthreads();
    bhalf8 af[8];
    #pragma unroll
    for (int ks=0; ks<8; ks++)
      af[ks] = *(const bhalf8*)&At[m16][ks*32 + quad*8];
    f32x4 acc[4];
    #pragma unroll
    for (int ct=0; ct<4; ct++) acc[ct] = (f32x4)(0.f);
    #pragma unroll
    for (int ks=0; ks<8; ks++){
      #pragma unroll
      for (int ct=0; ct<4; ct++){
        int f = (cg*16 + w*4 + ct)*8 + ks;
        bhalf8 bf = *(const bhalf8*)&Wt[f*512 + lane*8];
        acc[ct] = __builtin_amdgcn_mfma_f32_16x16x32_bf16(af[ks], bf, acc[ct], 0,0,0);
      }
    }
    bool isz = (cg >= 2);
    float* outp = isz ? szT : xcrT;
    int cbase = (cg & 1)*256 + w*64;
    int bb = r0 >> 8, l0 = r0 & (LD-1);
    #pragma unroll
    for (int ct=0; ct<4; ct++){
      int col = cbase + ct*16 + m16;
      float4 v;
      if (isz){
        v.x = siluf(acc[ct][0]); v.y = siluf(acc[ct][1]);
        v.z = siluf(acc[ct][2]); v.w = siluf(acc[ct][3]);
      } else {
        v.x = acc[ct][0]; v.y = acc[ct][1]; v.z = acc[ct][2]; v.w = acc[ct][3];
      }
      *(float4*)&outp[(bb*DI + col)*LD + l0 + quad*4] = v;
    }
  } else {
    int r0 = (bi - 1024) * 16;
    for (int p=0;p<2;p++){
      int i = tid + 256*p;
      int r = i >> 5, oct = (i & 31)*8;
      *(uint4*)&At[r][oct] = *(const uint4*)&xbf[(r0+r)*DM + oct];
    }
    __syncthreads();
    bhalf8 af[8];
    #pragma unroll
    for (int ks=0; ks<8; ks++)
      af[ks] = *(const bhalf8*)&At[m16][ks*32 + quad*8];
    f32x4 acc[4];
    #pragma unroll
    for (int ct=0; ct<4; ct++) acc[ct] = (f32x4)(0.f);
    #pragma unroll
    for (int ks=0; ks<8; ks++){
      #pragma unroll
      for (int ct=0; ct<4; ct++){
        int f = (w*4 + ct)*8 + ks;
        bhalf8 bf = *(const bhalf8*)&scWt[f*512 + lane*8];
        acc[ct] = __builtin_amdgcn_mfma_f32_16x16x32_bf16(af[ks], bf, acc[ct], 0,0,0);
      }
    }
    #pragma unroll
    for (int ct=0; ct<4; ct++){
      #pragma unroll
      for (int e=0;e<4;e++){
        int row = quad*4 + e;
        int col = w*64 + ct*16 + m16;
        Dt[row][col] = acc[ct][e] + sc_b[col];
      }
    }
    __syncthreads();
    {
      int row = tid >> 4, seg = tid & 15;
      float s = 0.f, s2 = 0.f;
      #pragma unroll
      for (int i=0;i<4;i++){
        float4 v = *(const float4*)&Dt[row][seg*16 + i*4];
        s  += v.x+v.y+v.z+v.w;
        s2 += v.x*v.x + v.y*v.y + v.z*v.z + v.w*v.w;
      }
      red[row][seg] = s;
      __syncthreads();
      if (seg == 0){
        float t=0.f;
        #pragma unroll
        for (int i=0;i<16;i++) t += red[row][i];
        mu[row] = t * (1.f/DM);
      }
      __syncthreads();
      red[row][seg] = s2;
      __syncthreads();
      if (seg == 0){
        float t=0.f;
        #pragma unroll
        for (int i=0;i<16;i++) t += red[row][i];
        float m = mu[row];
        rs[row] = rsqrtf(t*(1.f/DM) - m*m + 1e-5f);
      }
    }
    __syncthreads();
    float gg = ln_g[tid], bb2 = ln_b[tid];
    #pragma unroll
    for (int r=0;r<16;r++)
      ident[(r0+r)*DM + tid] = (Dt[r][tid]-mu[r])*rs[r]*gg + bb2;
  }
}

// ================= fused conv + silu + x_dbl(MFMA) + dt (transposed I/O) =================
__global__ __launch_bounds__(256) void k_convdbl(
    const float* __restrict__ cw_spa, const float* __restrict__ cb_spa,
    const float* __restrict__ cw_spe, const float* __restrict__ cb_spe,
    const float* __restrict__ xcrT,
    const unsigned short* __restrict__ Wxt_spa, const unsigned short* __restrict__ Wxt_spe,
    const float* __restrict__ Wdt_spa, const float* __restrict__ bdt_spa,
    const float* __restrict__ Wdt_spe, const float* __restrict__ bdt_spe,
    float* __restrict__ xcT, float* __restrict__ dtT,
    float* __restrict__ BmT, float* __restrict__ CmT)
{
  __shared__ unsigned short At[16][520];   // 16.6 KB
  __shared__ float xdbl[16][18];
  int tid = threadIdx.x;
  int r0 = blockIdx.x * 16;
  int branch = r0 >= HALF_ROWS;
  int bb = r0 >> 8;
  int l0 = r0 & (LD-1);
  const float* cw = branch ? cw_spe : cw_spa;
  const float* cb = branch ? cb_spe : cb_spa;
  const unsigned short* Wxt = branch ? Wxt_spe : Wxt_spa;
  const float* Wdt = branch ? Wdt_spe : Wdt_spa;
  const float* bdt = branch ? bdt_spe : bdt_spa;
  // conv phase: thread owns cols 2t, 2t+1; contiguous reads in l
  {
    int c0 = tid*2;
    float v0[16], v1[16];
    #pragma unroll
    for (int cc=0; cc<2; cc++){
      int c = c0 + cc;
      const float* src = xcrT + (bb*DI + c)*LD;
      float4 cwv = *(const float4*)(cw + 4*c);
      float bias = cb[c];
      float x[19];
      if (l0 > 0){
        x[0] = src[l0-3]; x[1] = src[l0-2]; x[2] = src[l0-1];
      } else { x[0]=0.f; x[1]=0.f; x[2]=0.f; }
      #pragma unroll
      for (int q=0;q<4;q++){
        float4 v = *(const float4*)(src + l0 + q*4);
        x[3+q*4+0]=v.x; x[3+q*4+1]=v.y; x[3+q*4+2]=v.z; x[3+q*4+3]=v.w;
      }
      float* dst = cc ? v1 : v0;
      #pragma unroll
      for (int r=0;r<16;r++){
        float a = bias;
        a = fmaf(x[r+0], cwv.x, a);
        a = fmaf(x[r+1], cwv.y, a);
        a = fmaf(x[r+2], cwv.z, a);
        a = fmaf(x[r+3], cwv.w, a);
        dst[r] = siluf(a);
      }
    }
    // write xcT (transposed, contiguous float4) + LDS At (row-major bf16)
    float* d0p = xcT + (bb*DI + c0)*LD + l0;
    float* d1p = xcT + (bb*DI + c0+1)*LD + l0;
    #pragma unroll
    for (int q=0;q<4;q++){
      *(float4*)(d0p + q*4) = make_float4(v0[q*4],v0[q*4+1],v0[q*4+2],v0[q*4+3]);
      *(float4*)(d1p + q*4) = make_float4(v1[q*4],v1[q*4+1],v1[q*4+2],v1[q*4+3]);
    }
    #pragma unroll
    for (int r=0;r<16;r++){
      unsigned int pk = (unsigned int)f2bf(v0[r]) | ((unsigned int)f2bf(v1[r]) << 16);
      *(unsigned int*)&At[r][c0] = pk;
    }
  }
  __syncthreads();
  int w = tid >> 6, lane = tid & 63;
  int m16 = lane & 15, quad = lane >> 4;
  f32x4 acc = (f32x4)(0.f);
  #pragma unroll
  for (int ks=0; ks<16; ks++){
    bhalf8 a = *(const bhalf8*)&At[m16][ks*32 + quad*8];
    int f = w*16 + ks;
    bhalf8 bf = *(const bhalf8*)&Wxt[f*512 + lane*8];
    acc = __builtin_amdgcn_mfma_f32_16x16x32_bf16(a, bf, acc, 0,0,0);
  }
  if (w == 0){
    #pragma unroll
    for (int e=0;e<4;e++) xdbl[quad*4 + e][m16] = acc[e];
  } else if (w == 1){
    *(float4*)&BmT[(bb*DS + m16)*LD + l0 + quad*4] = make_float4(acc[0],acc[1],acc[2],acc[3]);
  } else if (w == 2){
    *(float4*)&CmT[(bb*DS + m16)*LD + l0 + quad*4] = make_float4(acc[0],acc[1],acc[2],acc[3]);
  }
  __syncthreads();
  // dt GEMM: thread owns cols tid, tid+256; transposed float4 stores
  float wdt0[16], wdt1[16];
  #pragma unroll
  for (int j=0;j<16;j++){ wdt0[j]=Wdt[j*DI+tid]; wdt1[j]=Wdt[j*DI+tid+256]; }
  float b0 = bdt[tid], b1 = bdt[tid+256];
  float dv0[16], dv1[16];
  #pragma unroll
  for (int r=0;r<16;r++){
    float a0=b0, a1=b1;
    #pragma unroll
    for (int j=0;j<16;j++){
      float xv = xdbl[r][j];
      a0 = fmaf(xv, wdt0[j], a0);
      a1 = fmaf(xv, wdt1[j], a1);
    }
    dv0[r] = softplusf(a0);
    dv1[r] = softplusf(a1);
  }
  float* t0 = dtT + (bb*DI + tid)*LD + l0;
  float* t1 = dtT + (bb*DI + tid + 256)*LD + l0;
  #pragma unroll
  for (int q=0;q<4;q++){
    *(float4*)(t0 + q*4) = make_float4(dv0[q*4],dv0[q*4+1],dv0[q*4+2],dv0[q*4+3]);
    *(float4*)(t1 + q*4) = make_float4(dv1[q*4],dv1[q*4+1],dv1[q*4+2],dv1[q*4+3]);
  }
}

// ================= selective scan v8: transposed float4 inputs =================
__global__ __launch_bounds__(256) void k_scan(
    const float* __restrict__ Alog_spa, const float* __restrict__ Dp_spa,
    const float* __restrict__ Alog_spe, const float* __restrict__ Dp_spe,
    const float* __restrict__ dtT, const float* __restrict__ xcT,
    const float* __restrict__ szT, const float* __restrict__ BmT,
    const float* __restrict__ CmT, unsigned short* __restrict__ ybf)
{
  __shared__ float ypbuf[2][16][257];   // 32.9 KB, double-buffered
  __shared__ float Dsh[16];
  int tid = threadIdx.x;
  int bi = blockIdx.x;
  int branch = bi >> 8;
  int rem = bi & 255;
  int b = rem >> 5;
  int d0 = (rem & 31) * 16;
  const float* Alog = branch ? Alog_spe : Alog_spa;
  const float* Dp   = branch ? Dp_spe   : Dp_spa;
  int dg = tid >> 4, s = tid & 15;
  int d = d0 + dg;
  float A_ds = -__expf(Alog[d*DS + s]);
  if (tid < 16) Dsh[tid] = Dp[d0 + tid];
  int bb = branch*BD + b;
  int row0 = branch*HALF_ROWS + b*LD;
  const float* dtp = dtT + (bb*DI + d)*LD;
  const float* xcp = xcT + (bb*DI + d)*LD;
  const float* szp = szT + (bb*DI + d)*LD;
  const float* Bp  = BmT + (bb*DS + s)*LD;
  const float* Cp  = CmT + (bb*DS + s)*LD;
  int wcol = s*16 + ((dg + s) & 15);
  float h = 0.f;
  for (int c=0; c<16; c++){
    int l0c = c*16;
    int buf = c & 1;
    float rdt[16], rxc[16], rB[16], rC[16];
    #pragma unroll
    for (int q=0;q<4;q++){
      *(float4*)&rdt[q*4] = *(const float4*)(dtp + l0c + q*4);
      *(float4*)&rxc[q*4] = *(const float4*)(xcp + l0c + q*4);
      *(float4*)&rB[q*4]  = *(const float4*)(Bp  + l0c + q*4);
      *(float4*)&rC[q*4]  = *(const float4*)(Cp  + l0c + q*4);
    }
    float yp[16];
    #pragma unroll
    for (int li=0; li<16; li++){
      float dA = __expf(rdt[li] * A_ds);
      h = fmaf(dA, h, rdt[li] * rB[li] * rxc[li]);
      yp[li] = h * rC[li];
    }
    #pragma unroll
    for (int li=0; li<16; li++)
      ypbuf[buf][li][wcol] = yp[li];
    __syncthreads();
    float acc = 0.f;
    #pragma unroll
    for (int ss=0; ss<16; ss++)
      acc += ypbuf[buf][s][ss*16 + ((dg + ss) & 15)];
    float xcv = rxc[s];
    float szv = szp[l0c + s];
    float yv = fmaf(xcv, Dsh[dg], acc) * szv;
    ybf[(row0 + l0c + s)*DI + d0 + dg] = f2bf(yv);
  }
}

// ================= W_out GEMM + relu + residual + pool-accumulate (MFMA) =================
__global__ __launch_bounds__(256) void k_wout(
    const unsigned short* __restrict__ Wt_spa, const unsigned short* __restrict__ Wt_spe,
    const float* __restrict__ x_spa, const float* __restrict__ x_spe,
    const unsigned short* __restrict__ ybf, float* __restrict__ ae,
    float* __restrict__ pooled)
{
  __shared__ unsigned short At[16][520];   // 16.6 KB
  int tid = threadIdx.x;
  int bi = blockIdx.x;
  int r0 = (bi >> 1) * 16;
  int ch = bi & 1;
  int branch = (r0 >= HALF_ROWS);
  const unsigned short* Wt = branch ? Wt_spe : Wt_spa;
  const float* xb = branch ? x_spe : x_spa;
  int rr0 = branch ? r0 - HALF_ROWS : r0;
  for (int p=0;p<4;p++){
    int i = tid + 256*p;
    int r = i >> 6, oct = (i & 63)*8;
    *(uint4*)&At[r][oct] = *(const uint4*)&ybf[(r0+r)*DI + oct];
  }
  __syncthreads();
  int w = tid >> 6, lane = tid & 63;
  int m16 = lane & 15, quad = lane >> 4;
  bhalf8 af[16];
  #pragma unroll
  for (int ks=0; ks<16; ks++)
    af[ks] = *(const bhalf8*)&At[m16][ks*32 + quad*8];
  f32x4 acc[2];
  #pragma unroll
  for (int ct=0; ct<2; ct++) acc[ct] = (f32x4)(0.f);
  #pragma unroll
  for (int ks=0; ks<16; ks++){
    #pragma unroll
    for (int ct=0; ct<2; ct++){
      int f = (ch*8 + w*2 + ct)*16 + ks;
      bhalf8 bf = *(const bhalf8*)&Wt[f*512 + lane*8];
      acc[ct] = __builtin_amdgcn_mfma_f32_16x16x32_bf16(af[ks], bf, acc[ct], 0,0,0);
    }
  }
  float ps0 = 0.f, ps1 = 0.f;
  #pragma unroll
  for (int ct=0; ct<2; ct++){
    #pragma unroll
    for (int e=0;e<4;e++){
      int row = quad*4 + e;
      int col = ch*128 + w*32 + ct*16 + m16;
      float v = fmaxf(acc[ct][e], 0.f) + xb[(rr0+row)*DM + col];
      ae[(r0+row)*DM + col] = v;
      if (ct == 0) ps0 += v; else ps1 += v;
    }
  }
  ps0 += __shfl_xor(ps0, 16, 64); ps0 += __shfl_xor(ps0, 32, 64);
  ps1 += __shfl_xor(ps1, 16, 64); ps1 += __shfl_xor(ps1, 32, 64);
  if (quad == 0){
    int bidx = (r0 >> 8) & 7;
    atomicAdd(&pooled[bidx*DM + ch*128 + w*32 + m16],      ps0);
    atomicAdd(&pooled[bidx*DM + ch*128 + w*32 + 16 + m16], ps1);
  }
}

// ================= gate + final fused: 128 blocks, 32 rows each =================
__global__ __launch_bounds__(256) void k_gatefinal(const float* __restrict__ pooled,
    const float* __restrict__ fW, const float* __restrict__ ae,
    const float* __restrict__ ident, float* __restrict__ out)
{
  __shared__ float p[DM];
  __shared__ float fwsh[DM];
  int bi = blockIdx.x, c = threadIdx.x;
  int r0 = bi * 32;                 // global row 0..4095
  int b = (r0 >> 8) & 7;
  p[c] = pooled[b*DM+c] * (0.5f/LD);
  __syncthreads();
  float a = 0.f;
  for (int k=0;k<DM;k+=4){
    a = fmaf(p[k+0], fW[(k+0)*DM+c], a);
    a = fmaf(p[k+1], fW[(k+1)*DM+c], a);
    a = fmaf(p[k+2], fW[(k+2)*DM+c], a);
    a = fmaf(p[k+3], fW[(k+3)*DM+c], a);
  }
  fwsh[c] = 1.f/(1.f+__expf(-a));
  __syncthreads();
  // apply: 32 rows x 64 float4 = 2048 float4 / 256 thr = 8 each
  for (int q=0;q<8;q++){
    int i4 = c + 256*q;
    int r = i4 >> 6, c4 = (i4 & 63)*4;
    int base = (r0 + r)*DM + c4;
    float4 av = *(const float4*)(ae + base);
    float4 iv = *(const float4*)(ident + base);
    float4 fv = *(const float4*)&fwsh[c4];
    float4 o;
    o.x = fmaf(av.x, fv.x, iv.x);
    o.y = fmaf(av.y, fv.y, iv.y);
    o.z = fmaf(av.z, fv.z, iv.z);
    o.w = fmaf(av.w, fv.w, iv.w);
    *(float4*)(out + base) = o;
  }
}

extern "C" void kernel_launch(void* const* d_in, const int* in_sizes, int n_in,
                              void* d_out, int out_size, void* d_ws, size_t ws_size,
                              hipStream_t stream) {
  const float* x_spa     = (const float*)d_in[0];
  const float* x_spe     = (const float*)d_in[1];
  const float* spa_ln_g  = (const float*)d_in[2];
  const float* spa_ln_b  = (const float*)d_in[3];
  const float* spa_W_in  = (const float*)d_in[4];
  const float* spa_cw    = (const float*)d_in[5];
  const float* spa_cb    = (const float*)d_in[6];
  const float* spa_W_x   = (const float*)d_in[7];
  const float* spa_W_dt  = (const float*)d_in[8];
  const float* spa_b_dt  = (const float*)d_in[9];
  const float* spa_A_log = (const float*)d_in[10];
  const float* spa_D     = (const float*)d_in[11];
  const float* spa_W_out = (const float*)d_in[12];
  const float* spe_ln_g  = (const float*)d_in[13];
  const float* spe_ln_b  = (const float*)d_in[14];
  const float* spe_W_in  = (const float*)d_in[15];
  const float* spe_cw    = (const float*)d_in[16];
  const float* spe_cb    = (const float*)d_in[17];
  const float* spe_W_x   = (const float*)d_in[18];
  const float* spe_W_dt  = (const float*)d_in[19];
  const float* spe_b_dt  = (const float*)d_in[20];
  const float* spe_A_log = (const float*)d_in[21];
  const float* spe_D     = (const float*)d_in[22];
  const float* spe_W_out = (const float*)d_in[23];
  const float* sc_W      = (const float*)d_in[24];
  const float* sc_b      = (const float*)d_in[25];
  const float* sc_ln_g   = (const float*)d_in[26];
  const float* sc_ln_b   = (const float*)d_in[27];
  const float* fusion_W  = (const float*)d_in[28];

  float* ws = (float*)d_ws;
  float* ident  = ws;                       // 4096*256
  float* xcrT   = ident  + NROWS*DM;        // 4096*512 (reused as ybf)
  float* szT    = xcrT   + NROWS*DI;        // 4096*512
  float* xcT    = szT    + NROWS*DI;        // 4096*512
  float* dtT    = xcT    + NROWS*DI;        // 4096*512 (reused as ae)
  float* BmT    = dtT    + NROWS*DI;        // 4096*16
  float* CmT    = BmT    + NROWS*DS;        // 4096*16
  float* pooled = CmT    + NROWS*DS;        // 8*256
  float* fw     = pooled + BD*DM;           // 8*256 (unused)
  unsigned short* Wt_i_spa = (unsigned short*)(fw + BD*DM);
  unsigned short* Wt_i_spe = Wt_i_spa + 1024*256;
  unsigned short* Wt_o_spa = Wt_i_spe + 1024*256;
  unsigned short* Wt_o_spe = Wt_o_spa + 256*512;
  unsigned short* scWt     = Wt_o_spe + 256*512;
  unsigned short* Wxt_spa  = scWt     + 256*256;
  unsigned short* Wxt_spe  = Wxt_spa  + 64*512;
  unsigned short* xnbf     = Wxt_spe  + 64*512;   // 4096*256 bf16
  unsigned short* xbf      = xnbf     + NROWS*DM; // 4096*256 bf16

  float* out = (float*)d_out;

  k_prep<<<317, 256, 0, stream>>>(spa_W_in, spe_W_in, spa_W_out, spe_W_out, sc_W,
                                  spa_W_x, spe_W_x, x_spa, x_spe,
                                  spa_ln_g, spa_ln_b, spe_ln_g, spe_ln_b,
                                  Wt_i_spa, Wt_i_spe, Wt_o_spa, Wt_o_spe, scWt,
                                  Wxt_spa, Wxt_spe, xnbf, xbf, pooled);
  k_gemm1<<<1280, 256, 0, stream>>>(xnbf, xbf, Wt_i_spa, Wt_i_spe, scWt, sc_b,
                                    sc_ln_g, sc_ln_b, xcrT, szT, ident);
  k_convdbl<<<NROWS/16, 256, 0, stream>>>(spa_cw, spa_cb, spe_cw, spe_cb, xcrT,
                                          Wxt_spa, Wxt_spe,
                                          spa_W_dt, spa_b_dt, spe_W_dt, spe_b_dt,
                                          xcT, dtT, BmT, CmT);
  unsigned short* ybf = (unsigned short*)xcrT;   // xcrT dead after k_convdbl
  k_scan<<<512, 256, 0, stream>>>(spa_A_log, spa_D, spe_A_log, spe_D,
                                  dtT, xcT, szT, BmT, CmT, ybf);
  float* ae = dtT;     // dtT dead after k_scan
  k_wout<<<512, 256, 0, stream>>>(Wt_o_spa, Wt_o_spe, x_spa, x_spe, ybf, ae, pooled);
  k_gatefinal<<<128, 256, 0, stream>>>(pooled, fusion_W, ae, ident, out);
}

// Round 12
// 196.712 us; speedup vs baseline: 1.1667x; 1.1667x over previous
//
#include <hip/hip_runtime.h>
#include <hip/hip_bf16.h>
#include <math.h>

#define BD 8      // B
#define LD 256    // L
#define DM 256    // D_MODEL
#define DS 16     // D_STATE
#define DI 512    // D_INNER
#define RK 16     // DT_RANK

#define NROWS (2*BD*LD)   // 4096 rows (both branches concatenated)
#define HALF_ROWS (BD*LD) // 2048

typedef __attribute__((ext_vector_type(8))) short bhalf8;   // 8 bf16 = 4 VGPR
typedef __attribute__((ext_vector_type(4))) float f32x4;

__device__ __forceinline__ float siluf(float x){ return x / (1.f + __expf(-x)); }
__device__ __forceinline__ float softplusf(float x){
  return fmaxf(x, 0.f) + log1pf(__expf(-fabsf(x)));
}
__device__ __forceinline__ unsigned short f2bf(float f){
  __hip_bfloat16 h = __float2bfloat16(f);   // RNE
  return *reinterpret_cast<unsigned short*>(&h);
}

// Fragment-ordered weight layout: flat = ((ct*(K/32)+ks)*64 + quad*16 + m16)*8 + j
// so a wave B-load is W + f*512 + lane*8  (fully coalesced 1KB).
// Activations stay ROW-MAJOR: transposing them (R10 experiment) wrecked L2 locality.

// ================= prep: weights -> fragment-order bf16, LN of x, zero pooled =================
__global__ __launch_bounds__(256) void k_prep(
    const float* __restrict__ Wi_spa, const float* __restrict__ Wi_spe,
    const float* __restrict__ Wo_spa, const float* __restrict__ Wo_spe,
    const float* __restrict__ scW,
    const float* __restrict__ Wx_spa, const float* __restrict__ Wx_spe,
    const float* __restrict__ x_spa, const float* __restrict__ x_spe,
    const float* __restrict__ g_spa, const float* __restrict__ b_spa,
    const float* __restrict__ g_spe, const float* __restrict__ b_spe,
    unsigned short* __restrict__ Wt_i_spa, unsigned short* __restrict__ Wt_i_spe,
    unsigned short* __restrict__ Wt_o_spa, unsigned short* __restrict__ Wt_o_spe,
    unsigned short* __restrict__ scWt,
    unsigned short* __restrict__ Wxt_spa, unsigned short* __restrict__ Wxt_spe,
    unsigned short* __restrict__ xnbf, unsigned short* __restrict__ xbf,
    float* __restrict__ pooled)
{
  __shared__ __align__(16) unsigned char smem[59904];
  int b = blockIdx.x;
  int tid = threadIdx.x;
  if (b == 60){
    for (int i=tid; i<BD*DM; i+=256) pooled[i] = 0.f;
    return;
  }
  if (b >= 61){
    float (*xst)[260] = (float (*)[260])smem;
    float (*red)[16]  = (float (*)[16])(smem + 16640);
    float *mu = (float*)(smem + 17664);
    float *rs = (float*)(smem + 17728);
    int r0g = (b - 61) * 16;
    int branch = r0g >= HALF_ROWS;
    const float* xb = branch ? x_spe : x_spa;
    const float* g  = branch ? g_spe : g_spa;
    const float* be = branch ? b_spe : b_spa;
    int rr0 = branch ? r0g - HALF_ROWS : r0g;
    for (int p=0;p<4;p++){
      int i4 = tid + 256*p;
      int r = i4 >> 6, c4 = (i4 & 63)*4;
      *(float4*)&xst[r][c4] = *(const float4*)(xb + (rr0+r)*DM + c4);
    }
    __syncthreads();
    {
      int row = tid >> 4, seg = tid & 15;
      float s = 0.f, s2 = 0.f;
      #pragma unroll
      for (int i=0;i<4;i++){
        float4 v = *(float4*)&xst[row][seg*16 + i*4];
        s  += v.x+v.y+v.z+v.w;
        s2 += v.x*v.x + v.y*v.y + v.z*v.z + v.w*v.w;
      }
      red[row][seg] = s;
      __syncthreads();
      if (seg == 0){
        float t=0.f;
        #pragma unroll
        for (int i=0;i<16;i++) t += red[row][i];
        mu[row] = t * (1.f/DM);
      }
      __syncthreads();
      red[row][seg] = s2;
      __syncthreads();
      if (seg == 0){
        float t=0.f;
        #pragma unroll
        for (int i=0;i<16;i++) t += red[row][i];
        float m = mu[row];
        rs[row] = rsqrtf(t*(1.f/DM) - m*m + 1e-6f);
      }
    }
    __syncthreads();
    for (int p=0;p<4;p++){
      int i4 = tid + 256*p;
      int r = i4 >> 6, c4 = (i4 & 63)*4;
      float4 v  = *(float4*)&xst[r][c4];
      float4 gv = *(const float4*)(g + c4);
      float4 bv = *(const float4*)(be + c4);
      float m = mu[r], rv = rs[r];
      unsigned int rlo = (unsigned int)f2bf(v.x) | ((unsigned int)f2bf(v.y) << 16);
      unsigned int rhi = (unsigned int)f2bf(v.z) | ((unsigned int)f2bf(v.w) << 16);
      *(uint2*)&xbf[(r0g+r)*DM + c4] = make_uint2(rlo, rhi);
      unsigned int nlo = (unsigned int)f2bf((v.x-m)*rv*gv.x + bv.x)
                       | ((unsigned int)f2bf((v.y-m)*rv*gv.y + bv.y) << 16);
      unsigned int nhi = (unsigned int)f2bf((v.z-m)*rv*gv.z + bv.z)
                       | ((unsigned int)f2bf((v.w-m)*rv*gv.w + bv.w) << 16);
      *(uint2*)&xnbf[(r0g+r)*DM + c4] = make_uint2(nlo, nhi);
    }
    return;
  }
  if (b >= 52){
    int bb = b - 52;
    int branch = bb >> 2, chunk = bb & 3;
    int k0 = chunk*128;
    const float* Wx = branch ? Wx_spe : Wx_spa;
    unsigned short* Wxt = branch ? Wxt_spe : Wxt_spa;
    float (*tile2)[49] = (float (*)[49])(smem + 34816);
    for (int i=tid; i<128*48; i+=256){
      int kk = i/48, c = i - kk*48;
      tile2[kk][c] = Wx[(k0+kk)*48 + c];
    }
    __syncthreads();
    for (int i=tid; i<64*128; i+=256){
      int cc = i >> 7, kk = i & 127;
      float v = (cc < 48) ? tile2[kk][cc] : 0.f;
      int kg = k0 + kk;
      int ct = cc >> 4, m16 = cc & 15;
      int ks = kg >> 5, quad = (kg >> 3) & 3, j = kg & 7;
      Wxt[((ct*16 + ks)*64 + quad*16 + m16)*8 + j] = f2bf(v);
    }
    return;
  }
  unsigned short (*tile)[68] = (unsigned short (*)[68])smem;
  const float* W; unsigned short* Wt; int N, K, c0, k0;
  if (b < 32){
    int bb = b & 15;
    W  = (b < 16) ? Wi_spa  : Wi_spe;
    Wt = (b < 16) ? Wt_i_spa: Wt_i_spe;
    N = 1024; K = 256; c0 = (bb >> 2)*256; k0 = (bb & 3)*64;
  } else if (b < 48){
    int bb = b - 32; int h = bb >> 3; bb &= 7;
    W  = h ? Wo_spe  : Wo_spa;
    Wt = h ? Wt_o_spe: Wt_o_spa;
    N = 256; K = 512; c0 = 0; k0 = bb*64;
  } else {
    int bb = b - 48;
    W = scW; Wt = scWt;
    N = 256; K = 256; c0 = 0; k0 = bb*64;
  }
  int c = c0 + tid;
  #pragma unroll 8
  for (int kk=0; kk<64; kk++)
    tile[tid][kk] = f2bf(W[(k0+kk)*N + c]);
  __syncthreads();
  int ksegs = K >> 5;
  for (int p=0; p<16; p++){
    int i = tid + 256*p;
    int cl = i >> 4, kq = (i & 15)*4;
    int cg = c0 + cl;
    int ct = cg >> 4, m16 = cg & 15;
    int kg = k0 + kq;
    int ks = kg >> 5, quad = (kg >> 3) & 3, j = kg & 7;
    uint2 v = *(const uint2*)&tile[cl][kq];
    *(uint2*)&Wt[((ct*ksegs + ks)*64 + quad*16 + m16)*8 + j] = v;
  }
}

// ================= merged W_in GEMM (bi<1024) + shortcut GEMM+LN (bi>=1024) =================
__global__ __launch_bounds__(256) void k_gemm1(
    const unsigned short* __restrict__ xnbf, const unsigned short* __restrict__ xbf,
    const unsigned short* __restrict__ Wt_spa, const unsigned short* __restrict__ Wt_spe,
    const unsigned short* __restrict__ scWt, const float* __restrict__ sc_b,
    const float* __restrict__ ln_g, const float* __restrict__ ln_b,
    float* __restrict__ xc_raw, float* __restrict__ szout, float* __restrict__ ident)
{
  __shared__ unsigned short At[16][264];   // 8.4 KB
  __shared__ float Dt[16][260];            // 16.6 KB (shortcut only)
  __shared__ float red[16][16];
  __shared__ float mu[16], rs[16];
  int tid = threadIdx.x;
  int bi = blockIdx.x;
  int w = tid >> 6, lane = tid & 63;
  int m16 = lane & 15, quad = lane >> 4;
  if (bi < 1024){
    int rg = bi >> 2, cg = bi & 3;
    int r0 = rg * 16;
    int branch = (r0 >= HALF_ROWS);
    const unsigned short* Wt = branch ? Wt_spe : Wt_spa;
    for (int p=0;p<2;p++){
      int i = tid + 256*p;
      int r = i >> 5, oct = (i & 31)*8;
      *(uint4*)&At[r][oct] = *(const uint4*)&xnbf[(r0+r)*DM + oct];
    }
    __syncthreads();
    bhalf8 af[8];
    #pragma unroll
    for (int ks=0; ks<8; ks++)
      af[ks] = *(const bhalf8*)&At[m16][ks*32 + quad*8];
    f32x4 acc[4];
    #pragma unroll
    for (int ct=0; ct<4; ct++) acc[ct] = (f32x4)(0.f);
    #pragma unroll
    for (int ks=0; ks<8; ks++){
      #pragma unroll
      for (int ct=0; ct<4; ct++){
        int f = (cg*16 + w*4 + ct)*8 + ks;
        bhalf8 bf = *(const bhalf8*)&Wt[f*512 + lane*8];
        acc[ct] = __builtin_amdgcn_mfma_f32_16x16x32_bf16(af[ks], bf, acc[ct], 0,0,0);
      }
    }
    bool isz = (cg >= 2);
    float* outp = isz ? szout : xc_raw;
    int cbase = (cg & 1)*256 + w*64;
    #pragma unroll
    for (int ct=0; ct<4; ct++){
      #pragma unroll
      for (int e=0;e<4;e++){
        int row = r0 + quad*4 + e;
        int col = cbase + ct*16 + m16;
        float v = acc[ct][e];
        if (isz) v = siluf(v);
        outp[row*DI + col] = v;
      }
    }
  } else {
    int r0 = (bi - 1024) * 16;
    for (int p=0;p<2;p++){
      int i = tid + 256*p;
      int r = i >> 5, oct = (i & 31)*8;
      *(uint4*)&At[r][oct] = *(const uint4*)&xbf[(r0+r)*DM + oct];
    }
    __syncthreads();
    bhalf8 af[8];
    #pragma unroll
    for (int ks=0; ks<8; ks++)
      af[ks] = *(const bhalf8*)&At[m16][ks*32 + quad*8];
    f32x4 acc[4];
    #pragma unroll
    for (int ct=0; ct<4; ct++) acc[ct] = (f32x4)(0.f);
    #pragma unroll
    for (int ks=0; ks<8; ks++){
      #pragma unroll
      for (int ct=0; ct<4; ct++){
        int f = (w*4 + ct)*8 + ks;
        bhalf8 bf = *(const bhalf8*)&scWt[f*512 + lane*8];
        acc[ct] = __builtin_amdgcn_mfma_f32_16x16x32_bf16(af[ks], bf, acc[ct], 0,0,0);
      }
    }
    #pragma unroll
    for (int ct=0; ct<4; ct++){
      #pragma unroll
      for (int e=0;e<4;e++){
        int row = quad*4 + e;
        int col = w*64 + ct*16 + m16;
        Dt[row][col] = acc[ct][e] + sc_b[col];
      }
    }
    __syncthreads();
    {
      int row = tid >> 4, seg = tid & 15;
      float s = 0.f, s2 = 0.f;
      #pragma unroll
      for (int i=0;i<4;i++){
        float4 v = *(const float4*)&Dt[row][seg*16 + i*4];
        s  += v.x+v.y+v.z+v.w;
        s2 += v.x*v.x + v.y*v.y + v.z*v.z + v.w*v.w;
      }
      red[row][seg] = s;
      __syncthreads();
      if (seg == 0){
        float t=0.f;
        #pragma unroll
        for (int i=0;i<16;i++) t += red[row][i];
        mu[row] = t * (1.f/DM);
      }
      __syncthreads();
      red[row][seg] = s2;
      __syncthreads();
      if (seg == 0){
        float t=0.f;
        #pragma unroll
        for (int i=0;i<16;i++) t += red[row][i];
        float m = mu[row];
        rs[row] = rsqrtf(t*(1.f/DM) - m*m + 1e-5f);
      }
    }
    __syncthreads();
    float gg = ln_g[tid], bb2 = ln_b[tid];
    #pragma unroll
    for (int r=0;r<16;r++)
      ident[(r0+r)*DM + tid] = (Dt[r][tid]-mu[r])*rs[r]*gg + bb2;
  }
}

// ================= fused conv + silu + x_dbl(MFMA) + dt =================
__global__ __launch_bounds__(256) void k_convdbl(
    const float* __restrict__ cw_spa, const float* __restrict__ cb_spa,
    const float* __restrict__ cw_spe, const float* __restrict__ cb_spe,
    const float* __restrict__ xc_raw,
    const unsigned short* __restrict__ Wxt_spa, const unsigned short* __restrict__ Wxt_spe,
    const float* __restrict__ Wdt_spa, const float* __restrict__ bdt_spa,
    const float* __restrict__ Wdt_spe, const float* __restrict__ bdt_spe,
    float* __restrict__ xc, float* __restrict__ dt,
    float* __restrict__ Bm, float* __restrict__ Cm)
{
  __shared__ unsigned short At[16][520];   // 16.6 KB
  __shared__ float xdbl[16][18];
  int tid = threadIdx.x;
  int r0 = blockIdx.x * 16;
  int branch = r0 >= HALF_ROWS;
  int l0 = r0 & (LD-1);
  const float* cw = branch ? cw_spe : cw_spa;
  const float* cb = branch ? cb_spe : cb_spa;
  const unsigned short* Wxt = branch ? Wxt_spe : Wxt_spa;
  const float* Wdt = branch ? Wdt_spe : Wdt_spa;
  const float* bdt = branch ? bdt_spe : bdt_spa;
  {
    int c = tid*2;
    float4 w0 = *(const float4*)(cw + 4*c);
    float4 w1 = *(const float4*)(cw + 4*(c+1));
    float2 bias = *(const float2*)(cb + c);
    float2 h0, h1, h2;
    if (l0 > 0){
      h0 = *(const float2*)(xc_raw + (r0-3)*DI + c);
      h1 = *(const float2*)(xc_raw + (r0-2)*DI + c);
      h2 = *(const float2*)(xc_raw + (r0-1)*DI + c);
    } else {
      h0 = make_float2(0.f,0.f); h1 = h0; h2 = h0;
    }
    #pragma unroll
    for (int r=0;r<16;r++){
      float2 cur = *(const float2*)(xc_raw + (r0+r)*DI + c);
      float vx = bias.x;
      vx = fmaf(h0.x, w0.x, vx); vx = fmaf(h1.x, w0.y, vx);
      vx = fmaf(h2.x, w0.z, vx); vx = fmaf(cur.x, w0.w, vx);
      float vy = bias.y;
      vy = fmaf(h0.y, w1.x, vy); vy = fmaf(h1.y, w1.y, vy);
      vy = fmaf(h2.y, w1.z, vy); vy = fmaf(cur.y, w1.w, vy);
      vx = siluf(vx); vy = siluf(vy);
      *(float2*)(xc + (r0+r)*DI + c) = make_float2(vx, vy);
      unsigned int pk = (unsigned int)f2bf(vx) | ((unsigned int)f2bf(vy) << 16);
      *(unsigned int*)&At[r][c] = pk;
      h0 = h1; h1 = h2; h2 = cur;
    }
  }
  __syncthreads();
  int w = tid >> 6, lane = tid & 63;
  int m16 = lane & 15, quad = lane >> 4;
  f32x4 acc = (f32x4)(0.f);
  #pragma unroll
  for (int ks=0; ks<16; ks++){
    bhalf8 a = *(const bhalf8*)&At[m16][ks*32 + quad*8];
    int f = w*16 + ks;
    bhalf8 bf = *(const bhalf8*)&Wxt[f*512 + lane*8];
    acc = __builtin_amdgcn_mfma_f32_16x16x32_bf16(a, bf, acc, 0,0,0);
  }
  #pragma unroll
  for (int e=0;e<4;e++){
    int row = quad*4 + e;
    float v = acc[e];
    if (w == 0)      xdbl[row][m16] = v;
    else if (w == 1) Bm[(r0+row)*DS + m16] = v;
    else if (w == 2) Cm[(r0+row)*DS + m16] = v;
  }
  __syncthreads();
  float wdt0[16], wdt1[16];
  #pragma unroll
  for (int j=0;j<16;j++){ wdt0[j]=Wdt[j*DI+tid]; wdt1[j]=Wdt[j*DI+tid+256]; }
  float b0 = bdt[tid], b1 = bdt[tid+256];
  #pragma unroll
  for (int r=0;r<16;r++){
    float a0=b0, a1=b1;
    #pragma unroll
    for (int j=0;j<16;j++){
      float xv = xdbl[r][j];
      a0 = fmaf(xv, wdt0[j], a0);
      a1 = fmaf(xv, wdt1[j], a1);
    }
    dt[(r0+r)*DI + tid]       = softplusf(a0);
    dt[(r0+r)*DI + tid + 256] = softplusf(a1);
  }
}

// ================= selective scan v7.1: register inputs + software prefetch =================
// 512 blocks x 256 thr; thread (dg=tid>>4, s=tid&15); 16 chunks of 16 rows.
__global__ __launch_bounds__(256) void k_scan(
    const float* __restrict__ Alog_spa, const float* __restrict__ Dp_spa,
    const float* __restrict__ Alog_spe, const float* __restrict__ Dp_spe,
    const float* __restrict__ dt, const float* __restrict__ xc,
    const float* __restrict__ sz, const float* __restrict__ Bm,
    const float* __restrict__ Cm, unsigned short* __restrict__ ybf)
{
  __shared__ float ypbuf[2][16][257];   // 32.9 KB, double-buffered
  __shared__ float Dsh[16];
  int tid = threadIdx.x;
  int bi = blockIdx.x;
  int branch = bi >> 8;
  int rem = bi & 255;
  int b = rem >> 5;
  int d0 = (rem & 31) * 16;
  const float* Alog = branch ? Alog_spe : Alog_spa;
  const float* Dp   = branch ? Dp_spe   : Dp_spa;
  int dg = tid >> 4, s = tid & 15;
  int d = d0 + dg;
  float A_ds = -__expf(Alog[d*DS + s]);
  if (tid < 16) Dsh[tid] = Dp[d0 + tid];
  int row0 = branch*HALF_ROWS + b*LD;
  int wcol = s*16 + ((dg + s) & 15);    // this thread's ypbuf write column
  float h = 0.f;
  float rdt[2][16], rxc[2][16], rB[2][16], rC[2][16], rsz[2];
  // preload chunk 0
  #pragma unroll
  for (int li=0; li<16; li++){
    rdt[0][li] = dt[(row0+li)*DI + d];
    rxc[0][li] = xc[(row0+li)*DI + d];
    rB[0][li]  = Bm[(row0+li)*DS + s];
    rC[0][li]  = Cm[(row0+li)*DS + s];
  }
  rsz[0] = sz[(row0+s)*DI + d0 + dg];
  #pragma unroll
  for (int c=0; c<16; c++){
    int buf = c & 1, nb = buf ^ 1;
    int rbase = row0 + c*16;
    // serial scan (critical path: exp + fma per step)
    float yp[16];
    #pragma unroll
    for (int li=0; li<16; li++){
      float dA = __expf(rdt[buf][li] * A_ds);
      h = fmaf(dA, h, rdt[buf][li] * rB[buf][li] * rxc[buf][li]);
      yp[li] = h * rC[buf][li];
    }
    // prefetch next chunk BEFORE barrier so latency overlaps reduction
    if (c < 15){
      int nbase = rbase + 16;
      #pragma unroll
      for (int li=0; li<16; li++){
        rdt[nb][li] = dt[(nbase+li)*DI + d];
        rxc[nb][li] = xc[(nbase+li)*DI + d];
        rB[nb][li]  = Bm[(nbase+li)*DS + s];
        rC[nb][li]  = Cm[(nbase+li)*DS + s];
      }
      rsz[nb] = sz[(nbase+s)*DI + d0 + dg];
    }
    #pragma unroll
    for (int li=0; li<16; li++)
      ypbuf[buf][li][wcol] = yp[li];
    __syncthreads();
    // reduce over s: thread (dg,s) -> row rbase+s, col d0+dg
    float acc = 0.f;
    #pragma unroll
    for (int ss=0; ss<16; ss++)
      acc += ypbuf[buf][s][ss*16 + ((dg + ss) & 15)];
    float yv = fmaf(rxc[buf][s], Dsh[dg], acc) * rsz[buf];
    ybf[(rbase+s)*DI + d0 + dg] = f2bf(yv);
    // no trailing barrier: double-buffered ypbuf; writes to the other buffer
    // are ordered against reads two chunks back by the intervening barrier.
  }
}

// ================= W_out GEMM + relu + residual + pool-accumulate (MFMA) =================
__global__ __launch_bounds__(256) void k_wout(
    const unsigned short* __restrict__ Wt_spa, const unsigned short* __restrict__ Wt_spe,
    const float* __restrict__ x_spa, const float* __restrict__ x_spe,
    const unsigned short* __restrict__ ybf, float* __restrict__ ae,
    float* __restrict__ pooled)
{
  __shared__ unsigned short At[16][520];   // 16.6 KB
  int tid = threadIdx.x;
  int bi = blockIdx.x;
  int r0 = (bi >> 1) * 16;
  int ch = bi & 1;
  int branch = (r0 >= HALF_ROWS);
  const unsigned short* Wt = branch ? Wt_spe : Wt_spa;
  const float* xb = branch ? x_spe : x_spa;
  int rr0 = branch ? r0 - HALF_ROWS : r0;
  for (int p=0;p<4;p++){
    int i = tid + 256*p;
    int r = i >> 6, oct = (i & 63)*8;
    *(uint4*)&At[r][oct] = *(const uint4*)&ybf[(r0+r)*DI + oct];
  }
  __syncthreads();
  int w = tid >> 6, lane = tid & 63;
  int m16 = lane & 15, quad = lane >> 4;
  bhalf8 af[16];
  #pragma unroll
  for (int ks=0; ks<16; ks++)
    af[ks] = *(const bhalf8*)&At[m16][ks*32 + quad*8];
  f32x4 acc[2];
  #pragma unroll
  for (int ct=0; ct<2; ct++) acc[ct] = (f32x4)(0.f);
  #pragma unroll
  for (int ks=0; ks<16; ks++){
    #pragma unroll
    for (int ct=0; ct<2; ct++){
      int f = (ch*8 + w*2 + ct)*16 + ks;
      bhalf8 bf = *(const bhalf8*)&Wt[f*512 + lane*8];
      acc[ct] = __builtin_amdgcn_mfma_f32_16x16x32_bf16(af[ks], bf, acc[ct], 0,0,0);
    }
  }
  float ps0 = 0.f, ps1 = 0.f;
  #pragma unroll
  for (int ct=0; ct<2; ct++){
    #pragma unroll
    for (int e=0;e<4;e++){
      int row = quad*4 + e;
      int col = ch*128 + w*32 + ct*16 + m16;
      float v = fmaxf(acc[ct][e], 0.f) + xb[(rr0+row)*DM + col];
      ae[(r0+row)*DM + col] = v;
      if (ct == 0) ps0 += v; else ps1 += v;
    }
  }
  ps0 += __shfl_xor(ps0, 16, 64); ps0 += __shfl_xor(ps0, 32, 64);
  ps1 += __shfl_xor(ps1, 16, 64); ps1 += __shfl_xor(ps1, 32, 64);
  if (quad == 0){
    int bidx = (r0 >> 8) & 7;
    atomicAdd(&pooled[bidx*DM + ch*128 + w*32 + m16],      ps0);
    atomicAdd(&pooled[bidx*DM + ch*128 + w*32 + 16 + m16], ps1);
  }
}

// ================= gate + final fused: 128 blocks, 32 rows each =================
__global__ __launch_bounds__(256) void k_gatefinal(const float* __restrict__ pooled,
    const float* __restrict__ fW, const float* __restrict__ ae,
    const float* __restrict__ ident, float* __restrict__ out)
{
  __shared__ float p[DM];
  __shared__ float fwsh[DM];
  int bi = blockIdx.x, c = threadIdx.x;
  int r0 = bi * 32;                 // global row 0..4095
  int b = (r0 >> 8) & 7;
  p[c] = pooled[b*DM+c] * (0.5f/LD);
  __syncthreads();
  float a = 0.f;
  for (int k=0;k<DM;k+=4){
    a = fmaf(p[k+0], fW[(k+0)*DM+c], a);
    a = fmaf(p[k+1], fW[(k+1)*DM+c], a);
    a = fmaf(p[k+2], fW[(k+2)*DM+c], a);
    a = fmaf(p[k+3], fW[(k+3)*DM+c], a);
  }
  fwsh[c] = 1.f/(1.f+__expf(-a));
  __syncthreads();
  for (int q=0;q<8;q++){
    int i4 = c + 256*q;
    int r = i4 >> 6, c4 = (i4 & 63)*4;
    int base = (r0 + r)*DM + c4;
    float4 av = *(const float4*)(ae + base);
    float4 iv = *(const float4*)(ident + base);
    float4 fv = *(const float4*)&fwsh[c4];
    float4 o;
    o.x = fmaf(av.x, fv.x, iv.x);
    o.y = fmaf(av.y, fv.y, iv.y);
    o.z = fmaf(av.z, fv.z, iv.z);
    o.w = fmaf(av.w, fv.w, iv.w);
    *(float4*)(out + base) = o;
  }
}

extern "C" void kernel_launch(void* const* d_in, const int* in_sizes, int n_in,
                              void* d_out, int out_size, void* d_ws, size_t ws_size,
                              hipStream_t stream) {
  const float* x_spa     = (const float*)d_in[0];
  const float* x_spe     = (const float*)d_in[1];
  const float* spa_ln_g  = (const float*)d_in[2];
  const float* spa_ln_b  = (const float*)d_in[3];
  const float* spa_W_in  = (const float*)d_in[4];
  const float* spa_cw    = (const float*)d_in[5];
  const float* spa_cb    = (const float*)d_in[6];
  const float* spa_W_x   = (const float*)d_in[7];
  const float* spa_W_dt  = (const float*)d_in[8];
  const float* spa_b_dt  = (const float*)d_in[9];
  const float* spa_A_log = (const float*)d_in[10];
  const float* spa_D     = (const float*)d_in[11];
  const float* spa_W_out = (const float*)d_in[12];
  const float* spe_ln_g  = (const float*)d_in[13];
  const float* spe_ln_b  = (const float*)d_in[14];
  const float* spe_W_in  = (const float*)d_in[15];
  const float* spe_cw    = (const float*)d_in[16];
  const float* spe_cb    = (const float*)d_in[17];
  const float* spe_W_x   = (const float*)d_in[18];
  const float* spe_W_dt  = (const float*)d_in[19];
  const float* spe_b_dt  = (const float*)d_in[20];
  const float* spe_A_log = (const float*)d_in[21];
  const float* spe_D     = (const float*)d_in[22];
  const float* spe_W_out = (const float*)d_in[23];
  const float* sc_W      = (const float*)d_in[24];
  const float* sc_b      = (const float*)d_in[25];
  const float* sc_ln_g   = (const float*)d_in[26];
  const float* sc_ln_b   = (const float*)d_in[27];
  const float* fusion_W  = (const float*)d_in[28];

  float* ws = (float*)d_ws;
  float* ident  = ws;                       // 4096*256
  float* xc_raw = ident  + NROWS*DM;        // 4096*512 (reused as ybf)
  float* sz     = xc_raw + NROWS*DI;        // 4096*512
  float* xc     = sz     + NROWS*DI;        // 4096*512
  float* dt     = xc     + NROWS*DI;        // 4096*512 (reused as ae)
  float* Bm     = dt     + NROWS*DI;        // 4096*16
  float* Cm     = Bm     + NROWS*DS;        // 4096*16
  float* pooled = Cm     + NROWS*DS;        // 8*256
  float* fw     = pooled + BD*DM;           // 8*256 (unused)
  unsigned short* Wt_i_spa = (unsigned short*)(fw + BD*DM);
  unsigned short* Wt_i_spe = Wt_i_spa + 1024*256;
  unsigned short* Wt_o_spa = Wt_i_spe + 1024*256;
  unsigned short* Wt_o_spe = Wt_o_spa + 256*512;
  unsigned short* scWt     = Wt_o_spe + 256*512;
  unsigned short* Wxt_spa  = scWt     + 256*256;
  unsigned short* Wxt_spe  = Wxt_spa  + 64*512;
  unsigned short* xnbf     = Wxt_spe  + 64*512;   // 4096*256 bf16
  unsigned short* xbf      = xnbf     + NROWS*DM; // 4096*256 bf16

  float* out = (float*)d_out;

  k_prep<<<317, 256, 0, stream>>>(spa_W_in, spe_W_in, spa_W_out, spe_W_out, sc_W,
                                  spa_W_x, spe_W_x, x_spa, x_spe,
                                  spa_ln_g, spa_ln_b, spe_ln_g, spe_ln_b,
                                  Wt_i_spa, Wt_i_spe, Wt_o_spa, Wt_o_spe, scWt,
                                  Wxt_spa, Wxt_spe, xnbf, xbf, pooled);
  k_gemm1<<<1280, 256, 0, stream>>>(xnbf, xbf, Wt_i_spa, Wt_i_spe, scWt, sc_b,
                                    sc_ln_g, sc_ln_b, xc_raw, sz, ident);
  k_convdbl<<<NROWS/16, 256, 0, stream>>>(spa_cw, spa_cb, spe_cw, spe_cb, xc_raw,
                                          Wxt_spa, Wxt_spe,
                                          spa_W_dt, spa_b_dt, spe_W_dt, spe_b_dt,
                                          xc, dt, Bm, Cm);
  unsigned short* ybf = (unsigned short*)xc_raw;   // xc_raw dead after k_convdbl
  k_scan<<<512, 256, 0, stream>>>(spa_A_log, spa_D, spe_A_log, spe_D, dt, xc, sz, Bm, Cm, ybf);
  float* ae = dt;      // dt dead after k_scan
  k_wout<<<512, 256, 0, stream>>>(Wt_o_spa, Wt_o_spe, x_spa, x_spe, ybf, ae, pooled);
  k_gatefinal<<<128, 256, 0, stream>>>(pooled, fusion_W, ae, ident, out);
}